// Round 10
// baseline (1654.562 us; speedup 1.0000x reference)
//
#include <hip/hip_runtime.h>
#include <hip/hip_fp16.h>
#include <math.h>

#define N_NODES 100000
#define N_EDGES 3200000
#define IN_DIM 11
#define HID 32
#define HID2 16
#define SCHUNK 100352   // per-array stride in ws (multiple of 128, >= N_NODES+1)
#define BINSHIFT 8
#define BINSZ 256
#define NB 391          // ceil(100000/256) bins (256 nodes each)
#define CHUNK 6144      // edges per chunk
#define NCH 521         // ceil(3200000/6144); 521*6144 = 3201024
#define NCH1 522        // cnthist row stride (incl. sentinel column)
#define NHALF 50000     // src-half boundary for L2 phase blocking

// ---------------- wave-shuffle scan utilities (wave = 64) ----------------
__device__ __forceinline__ int wincl(int v) {
    int lane = threadIdx.x & 63;
#pragma unroll
    for (int d = 1; d < 64; d <<= 1) {
        int u = __shfl_up(v, d, 64);
        v += (lane >= d) ? u : 0;
    }
    return v;
}

// exclusive prefix of v across 512 threads; wtot = LDS int[8]; 2 barriers
__device__ __forceinline__ int blkexcl512(int v, int* wtot) {
    int t = threadIdx.x, lane = t & 63, w = t >> 6;
    int inc = wincl(v);
    if (lane == 63) wtot[w] = inc;
    __syncthreads();
    if (t < 8) {
        int x = wtot[t], ix = x;
#pragma unroll
        for (int d = 1; d < 8; d <<= 1) {
            int u = __shfl_up(ix, d, 64);
            ix += (lane >= d) ? u : 0;
        }
        wtot[t] = ix - x;   // exclusive wave base
    }
    __syncthreads();
    return inc - v + wtot[w];
}

// ---------------- binned CSR-lite build ----------------
// Pass 1: per-chunk per-bin counts -> cnthist[bin][chunk]; plus global deg[]
__global__ __launch_bounds__(256) void k_hist(const int* __restrict__ ei,
                                              int* __restrict__ cnthist,
                                              int* __restrict__ deg) {
    __shared__ int h[NB];
    int t = threadIdx.x;
    for (int i = t; i < NB; i += 256) h[i] = 0;
    __syncthreads();
    int b0 = blockIdx.x * CHUNK;
    int n = N_EDGES - b0; if (n > CHUNK) n = CHUNK;   // always multiple of 4
    for (int e = t * 4; e < n; e += 1024) {
        int4 d4 = *(const int4*)(ei + N_EDGES + b0 + e);
        atomicAdd(&h[d4.x >> BINSHIFT], 1);
        atomicAdd(&h[d4.y >> BINSHIFT], 1);
        atomicAdd(&h[d4.z >> BINSHIFT], 1);
        atomicAdd(&h[d4.w >> BINSHIFT], 1);
        atomicAdd(&deg[d4.x], 1);
        atomicAdd(&deg[d4.y], 1);
        atomicAdd(&deg[d4.z], 1);
        atomicAdd(&deg[d4.w], 1);
    }
    __syncthreads();
    for (int i = t; i < NB; i += 256)
        cnthist[i * NCH1 + blockIdx.x] = h[i];
}

// Pass 2: per-bin exclusive scan over chunks (in-place) + sentinel column.
__global__ __launch_bounds__(256) void k_colscan(int* __restrict__ cnthist,
                                                 int* __restrict__ colsum) {
    __shared__ int wtot[4];
    int i = blockIdx.x;   // bin
    int t = threadIdx.x;
    int lane = t & 63;
    int v[4];
    int s4 = 0;
#pragma unroll
    for (int u = 0; u < 4; ++u) {
        int idx = t * 4 + u;
        v[u] = (idx < NCH) ? cnthist[i * NCH1 + idx] : 0;
        s4 += v[u];
    }
    int inc = wincl(s4);
    if (lane == 63) wtot[t >> 6] = inc;
    __syncthreads();
    if (t < 4) {
        int x = wtot[t], ix = x;
#pragma unroll
        for (int d = 1; d < 4; d <<= 1) {
            int u2 = __shfl_up(ix, d, 64);
            ix += (lane >= d) ? u2 : 0;
        }
        wtot[t] = ix - x;
    }
    __syncthreads();
    int base = inc - s4 + wtot[t >> 6];   // exclusive across 4-groups
#pragma unroll
    for (int u = 0; u < 4; ++u) {
        int idx = t * 4 + u;
        if (idx < NCH) cnthist[i * NCH1 + idx] = base;
        base += v[u];
    }
    if (t == 255) {                        // base here == bin total
        cnthist[i * NCH1 + NCH] = base;    // sentinel column
        colsum[i] = base;
    }
}

// Pass 3: scan of 391 bin totals -> binbase (single block)
__global__ __launch_bounds__(512) void k_scanbins(const int* __restrict__ colsum,
                                                  int* __restrict__ binbase) {
    __shared__ int wtot[8];
    int t = threadIdx.x;
    int v = (t < NB) ? colsum[t] : 0;
    int pre = blkexcl512(v, wtot);
    if (t < NB) binbase[t] = pre;
    if (t == 0) binbase[NB] = N_EDGES;   // sentinel
}

// Pass 4: scatter edges into bin buckets (LDS sort + clustered dump).
__global__ __launch_bounds__(512) void k_binscatter(const int* __restrict__ ei,
                                                    const int* __restrict__ binbase,
                                                    const int* __restrict__ cnthist,
                                                    unsigned* __restrict__ binbuf) {
    __shared__ unsigned       srecS[CHUNK];  // records at sorted position (24KB)
    __shared__ unsigned short sbinS[CHUNK];  // bin at sorted position     (12KB)
    __shared__ int h[NB], rl[NB], gb[NB];
    __shared__ int wtot[8];
    int t = threadIdx.x;
    int b0 = blockIdx.x * CHUNK;
    int n = N_EDGES - b0; if (n > CHUNK) n = CHUNK;
    int pre_b = 0, c = 0;
    if (t < NB) {
        pre_b = cnthist[t * NCH1 + blockIdx.x];
        c = cnthist[t * NCH1 + blockIdx.x + 1] - pre_b;
    }
    int rlv = blkexcl512(c, wtot);   // chunk-local sorted base per bin
    if (t < NB) {
        rl[t] = rlv;
        gb[t] = binbase[t] + pre_b;  // global dump base
        h[t] = 0;                    // cursor
    }
    __syncthreads();
    for (int e = t; e < n; e += 512) {
        int d = ei[N_EDGES + b0 + e];
        int s = ei[b0 + e];
        int b = d >> BINSHIFT;
        int p = rl[b] + atomicAdd(&h[b], 1);
        srecS[p] = (unsigned)s | ((unsigned)(d & (BINSZ - 1)) << 17);  // s < 2^17
        sbinS[p] = (unsigned short)b;
    }
    __syncthreads();
    for (int p = t; p < n; p += 512) {
        int b = sbinS[p];
        binbuf[gb[b] + (p - rl[b])] = srecS[p];
    }
}

// ---------------- dense transform 1 (dinv from deg; interleaved [node*32+j]) -----
__global__ void k_xw1(const float* __restrict__ x, const float* __restrict__ W1,
                      const int* __restrict__ deg, __half* __restrict__ xwh) {
    int t = blockIdx.x * blockDim.x + threadIdx.x;
    int node = t >> 5;
    int j = t & 31;
    __shared__ float sW[IN_DIM * HID];
    __shared__ float sx[8 * IN_DIM];
    for (int i = threadIdx.x; i < IN_DIM * HID; i += 256) sW[i] = W1[i];
    int base = blockIdx.x * 8;
    if (threadIdx.x < 8 * IN_DIM) sx[threadIdx.x] = x[base * IN_DIM + threadIdx.x];
    __syncthreads();
    int ln = node - base;
    float acc = 0.0f;
#pragma unroll
    for (int k = 0; k < IN_DIM; ++k)
        acc += sx[ln * IN_DIM + k] * sW[k * HID + j];
    float dd = rsqrtf((float)deg[node] + 1.0f);   // +1 self-loop
    xwh[t] = __float2half(dd * acc);
}

// ---------------- bin-major LDS-accumulate gather ----------------
// One block per bin: stream the bin's records (coalesced, NT), accumulate
// xwh[s][:] into acc[dl][:] via LDS f32 atomics (stride 33 spreads banks by
// dl).  Phase A takes s<NHALF only (XWH low half L2-hot; 391 blocks all
// co-resident so phases align), phase B the rest.  4 record-chains per
// thread keep misses in flight.  Degrees counted in cnt[] -> dinv in epilogue.
__device__ __forceinline__ void rec_proc(unsigned rec, int act, int oj,
                                         const __half* __restrict__ xwh,
                                         float (*acc)[33], int* cnt) {
    if (act) {
        int s = (int)(rec & 0x1FFFFu);
        int dl = (int)(rec >> 17);
        uint4 v = *(const uint4*)(xwh + ((s << 5) | oj));
        float2 f0 = __half22float2(*(const __half2*)&v.x);
        float2 f1 = __half22float2(*(const __half2*)&v.y);
        float2 f2 = __half22float2(*(const __half2*)&v.z);
        float2 f3 = __half22float2(*(const __half2*)&v.w);
        atomicAdd(&acc[dl][oj + 0], f0.x);
        atomicAdd(&acc[dl][oj + 1], f0.y);
        atomicAdd(&acc[dl][oj + 2], f1.x);
        atomicAdd(&acc[dl][oj + 3], f1.y);
        atomicAdd(&acc[dl][oj + 4], f2.x);
        atomicAdd(&acc[dl][oj + 5], f2.y);
        atomicAdd(&acc[dl][oj + 6], f3.x);
        atomicAdd(&acc[dl][oj + 7], f3.y);
        if (oj == 0) atomicAdd(&cnt[dl], 1);
    }
}

__device__ __forceinline__ void bin_accum(int ebeg, int eend, int slot, int oj,
                                          const unsigned* __restrict__ binbuf,
                                          const __half* __restrict__ xwh,
                                          float (*acc)[33], int* cnt) {
#pragma unroll 1
    for (int ph = 0; ph < 2; ++ph) {
#pragma unroll 1
        for (int e0 = ebeg + slot; e0 < eend; e0 += 512) {
            int e1 = e0 + 128, e2 = e0 + 256, e3 = e0 + 384;
            int in1 = e1 < eend, in2 = e2 < eend, in3 = e3 < eend;
            unsigned r0 = __builtin_nontemporal_load(binbuf + e0);
            unsigned r1 = in1 ? __builtin_nontemporal_load(binbuf + e1) : 0u;
            unsigned r2 = in2 ? __builtin_nontemporal_load(binbuf + e2) : 0u;
            unsigned r3 = in3 ? __builtin_nontemporal_load(binbuf + e3) : 0u;
            int a0 = (((int)(r0 & 0x1FFFFu) >= NHALF) == ph);
            int a1 = in1 && (((int)(r1 & 0x1FFFFu) >= NHALF) == ph);
            int a2 = in2 && (((int)(r2 & 0x1FFFFu) >= NHALF) == ph);
            int a3 = in3 && (((int)(r3 & 0x1FFFFu) >= NHALF) == ph);
            rec_proc(r0, a0, oj, xwh, acc, cnt);
            rec_proc(r1, a1, oj, xwh, acc, cnt);
            rec_proc(r2, a2, oj, xwh, acc, cnt);
            rec_proc(r3, a3, oj, xwh, acc, cnt);
        }
        __syncthreads();   // phase boundary (co-resident grid keeps blocks aligned)
    }
}

// layer-1: acc = gather(XWH1); H = relu(dinv*(acc+self)+b1); XWH2 = dinv*(H@W2)
__global__ __launch_bounds__(512) void k_gather_xw2(const int* __restrict__ binbase,
                                                    const unsigned* __restrict__ binbuf,
                                                    const __half* __restrict__ xwh1,
                                                    const float* __restrict__ b1,
                                                    const float* __restrict__ W2,
                                                    __half* __restrict__ xwh2) {
    __shared__ float acc[BINSZ][33];
    __shared__ int   cnt[BINSZ];
    __shared__ float dinvs[BINSZ];
    __shared__ float sW2[HID * HID];
    int b = blockIdx.x;
    int t = threadIdx.x;
    for (int i = t; i < HID * HID; i += 512) sW2[i] = W2[i];
    for (int i = t; i < BINSZ * 33; i += 512) (&acc[0][0])[i] = 0.0f;
    if (t < BINSZ) cnt[t] = 0;
    __syncthreads();
    int ebeg = binbase[b], eend = binbase[b + 1];
    int slot = t >> 2, oj = (t & 3) << 3;
    bin_accum(ebeg, eend, slot, oj, binbuf, xwh1, acc, cnt);

    // epilogue: H in place, then W2 transform
    int j = t & 31;
#pragma unroll 1
    for (int r = 0; r < 16; ++r) {
        int m = (t >> 5) + r * 16;
        int node = b * BINSZ + m;
        if (node < N_NODES) {
            float dd = rsqrtf((float)cnt[m] + 1.0f);
            float hv = dd * (acc[m][j] + __half2float(xwh1[node * HID + j])) + b1[j];
            acc[m][j] = hv > 0.0f ? hv : 0.0f;
            if (j == 0) dinvs[m] = dd;
        }
    }
    __syncthreads();
#pragma unroll 1
    for (int r = 0; r < 16; ++r) {
        int m = (t >> 5) + r * 16;
        int node = b * BINSZ + m;
        if (node < N_NODES) {
            float a2 = 0.0f;
#pragma unroll
            for (int k = 0; k < HID; ++k) a2 += acc[m][k] * sW2[k * HID + j];
            xwh2[node * HID + j] = __float2half(dinvs[m] * a2);
        }
    }
}

// layer-2: acc = gather(XWH2); H = relu(dinv*(acc+self)+b2); out = MLP(H)
__global__ __launch_bounds__(512) void k_gather_mlp(const int* __restrict__ binbase,
                                                    const unsigned* __restrict__ binbuf,
                                                    const __half* __restrict__ xwh,
                                                    const float* __restrict__ b2,
                                                    const float* __restrict__ Wo1,
                                                    const float* __restrict__ bo1,
                                                    const float* __restrict__ Wo2,
                                                    const float* __restrict__ bo2,
                                                    float* __restrict__ out) {
    __shared__ float acc[BINSZ][33];
    __shared__ int   cnt[BINSZ];
    __shared__ float sW1[HID * HID2];
    __shared__ float sb1[HID2];
    __shared__ float sW2v[HID2];
    __shared__ float sb2[HID];
    int b = blockIdx.x;
    int t = threadIdx.x;
    for (int i = t; i < HID * HID2; i += 512) sW1[i] = Wo1[i];
    if (t < HID2) { sb1[t] = bo1[t]; sW2v[t] = Wo2[t]; }
    if (t < HID) sb2[t] = b2[t];
    for (int i = t; i < BINSZ * 33; i += 512) (&acc[0][0])[i] = 0.0f;
    if (t < BINSZ) cnt[t] = 0;
    __syncthreads();
    int ebeg = binbase[b], eend = binbase[b + 1];
    int slot = t >> 2, oj = (t & 3) << 3;
    bin_accum(ebeg, eend, slot, oj, binbuf, xwh, acc, cnt);

    int j = t & 31;
#pragma unroll 1
    for (int r = 0; r < 16; ++r) {
        int m = (t >> 5) + r * 16;
        int node = b * BINSZ + m;
        if (node < N_NODES) {
            float dd = rsqrtf((float)cnt[m] + 1.0f);
            float hv = dd * (acc[m][j] + __half2float(xwh[node * HID + j])) + sb2[j];
            acc[m][j] = hv > 0.0f ? hv : 0.0f;
        }
    }
    __syncthreads();
#pragma unroll 1
    for (int r = 0; r < 16; ++r) {
        int m = (t >> 5) + r * 16;
        int node = b * BINSZ + m;
        float val = 0.0f;
        if (node < N_NODES && j < HID2) {
            float a = sb1[j];
#pragma unroll
            for (int k = 0; k < HID; ++k) a += acc[m][k] * sW1[k * HID2 + j];
            a = a > 0.0f ? a : (expf(a) - 1.0f);  // elu alpha=1
            val = a * sW2v[j];
        }
#pragma unroll
        for (int d = 16; d >= 1; d >>= 1) val += __shfl_down(val, d, 32);
        if (node < N_NODES && j == 0) out[node] = val + bo2[0];
    }
}

extern "C" void kernel_launch(void* const* d_in, const int* in_sizes, int n_in,
                              void* d_out, int out_size, void* d_ws, size_t ws_size,
                              hipStream_t stream) {
    const float* x   = (const float*)d_in[0];
    const int*   ei  = (const int*)d_in[1];
    const float* W1  = (const float*)d_in[3];
    const float* b1  = (const float*)d_in[4];
    const float* W2  = (const float*)d_in[5];
    const float* b2  = (const float*)d_in[6];
    const float* Wo1 = (const float*)d_in[7];
    const float* bo1 = (const float*)d_in[8];
    const float* Wo2 = (const float*)d_in[9];
    const float* bo2 = (const float*)d_in[10];
    float* out = (float*)d_out;

    // ws layout (4B units) -- offsets unchanged from r8:
    // colsum[512] | binbase[512] | (unused)[SCHUNK] | deg[SCHUNK]
    // | cnthist region (old csr_src slot, NB*NCH1=204102 ints)
    // | binbuf[E] | XWH1[N*HID fp16] | XWH2[N*HID fp16]
    int*      colsum   = (int*)d_ws;
    int*      binbase  = colsum + 512;
    int*      unused_  = binbase + 512;
    int*      deg      = unused_ + SCHUNK;
    int*      cnthist  = deg + SCHUNK;
    unsigned* binbuf   = (unsigned*)(cnthist + N_EDGES);
    __half*   XWH1     = (__half*)(binbuf + N_EDGES);
    __half*   XWH2     = XWH1 + (size_t)N_NODES * HID;

    const int BT = 256;
    int gNH = (N_NODES * HID + BT - 1) / BT;        // 12500

    // build: deg+hist -> colscan(+sentinel) -> binscan -> scatter
    hipMemsetAsync(deg, 0, N_NODES * sizeof(int), stream);
    k_hist      <<<NCH, BT, 0, stream>>>(ei, cnthist, deg);
    k_xw1       <<<gNH, BT, 0, stream>>>(x, W1, deg, XWH1);
    k_colscan   <<<NB, BT, 0, stream>>>(cnthist, colsum);
    k_scanbins  <<<1, 512, 0, stream>>>(colsum, binbase);
    k_binscatter<<<NCH, 512, 0, stream>>>(ei, binbase, cnthist, binbuf);

    // layer 1 (+ fused W2), bin-major: XWH2 = fp16(dinv.*(relu(gather+b1)@W2))
    k_gather_xw2<<<NB, 512, 0, stream>>>(binbase, binbuf, XWH1, b1, W2, XWH2);

    // layer 2 + head, bin-major: out = MLP(relu(dinv.*gather(XWH2) + b2))
    k_gather_mlp<<<NB, 512, 0, stream>>>(binbase, binbuf, XWH2,
                                         b2, Wo1, bo1, Wo2, bo2, out);
}

// Round 11
// 238.901 us; speedup vs baseline: 6.9257x; 6.9257x over previous
//
#include <hip/hip_runtime.h>
#include <hip/hip_fp16.h>
#include <math.h>

#define N_NODES 100000
#define N_EDGES 3200000
#define IN_DIM 11
#define HID 32
#define HID2 16
#define SCHUNK 100352   // per-array stride in ws (multiple of 128, >= N_NODES+1)
#define BINSHIFT 8
#define BINSZ 256
#define NB 391          // ceil(100000/256) bins (256 nodes each)
#define CHUNK 6144      // edges per chunk
#define NCH 521         // ceil(3200000/6144); 521*6144 = 3201024
#define NCH1 522        // cnthist row stride (incl. sentinel column)
#define FCAP 9216       // binfill LDS staging capacity (avg bin = 8184)

// ---------------- wave-shuffle scan utilities (wave = 64) ----------------
__device__ __forceinline__ int wincl(int v) {
    int lane = threadIdx.x & 63;
#pragma unroll
    for (int d = 1; d < 64; d <<= 1) {
        int u = __shfl_up(v, d, 64);
        v += (lane >= d) ? u : 0;
    }
    return v;
}

// exclusive prefix of v across 512 threads; wtot = LDS int[8]; 2 barriers
__device__ __forceinline__ int blkexcl512(int v, int* wtot) {
    int t = threadIdx.x, lane = t & 63, w = t >> 6;
    int inc = wincl(v);
    if (lane == 63) wtot[w] = inc;
    __syncthreads();
    if (t < 8) {
        int x = wtot[t], ix = x;
#pragma unroll
        for (int d = 1; d < 8; d <<= 1) {
            int u = __shfl_up(ix, d, 64);
            ix += (lane >= d) ? u : 0;
        }
        wtot[t] = ix - x;   // exclusive wave base
    }
    __syncthreads();
    return inc - v + wtot[w];
}

// ---------------- binned CSR build ----------------
// Pass 1: per-chunk per-bin counts -> cnthist[bin][chunk] (stride NCH1)
__global__ __launch_bounds__(256) void k_hist(const int* __restrict__ ei,
                                              int* __restrict__ cnthist) {
    __shared__ int h[NB];
    int t = threadIdx.x;
    for (int i = t; i < NB; i += 256) h[i] = 0;
    __syncthreads();
    int b0 = blockIdx.x * CHUNK;
    int n = N_EDGES - b0; if (n > CHUNK) n = CHUNK;   // always multiple of 4
    for (int e = t * 4; e < n; e += 1024) {
        int4 d4 = *(const int4*)(ei + N_EDGES + b0 + e);
        atomicAdd(&h[d4.x >> BINSHIFT], 1);
        atomicAdd(&h[d4.y >> BINSHIFT], 1);
        atomicAdd(&h[d4.z >> BINSHIFT], 1);
        atomicAdd(&h[d4.w >> BINSHIFT], 1);
    }
    __syncthreads();
    for (int i = t; i < NB; i += 256)
        cnthist[i * NCH1 + blockIdx.x] = h[i];
}

// Pass 2: per-bin exclusive scan over chunks (in-place) + sentinel column.
__global__ __launch_bounds__(256) void k_colscan(int* __restrict__ cnthist,
                                                 int* __restrict__ colsum) {
    __shared__ int wtot[4];
    int i = blockIdx.x;   // bin
    int t = threadIdx.x;
    int lane = t & 63;
    int v[4];
    int s4 = 0;
#pragma unroll
    for (int u = 0; u < 4; ++u) {
        int idx = t * 4 + u;
        v[u] = (idx < NCH) ? cnthist[i * NCH1 + idx] : 0;
        s4 += v[u];
    }
    int inc = wincl(s4);
    if (lane == 63) wtot[t >> 6] = inc;
    __syncthreads();
    if (t < 4) {
        int x = wtot[t], ix = x;
#pragma unroll
        for (int d = 1; d < 4; d <<= 1) {
            int u2 = __shfl_up(ix, d, 64);
            ix += (lane >= d) ? u2 : 0;
        }
        wtot[t] = ix - x;
    }
    __syncthreads();
    int base = inc - s4 + wtot[t >> 6];   // exclusive across 4-groups
#pragma unroll
    for (int u = 0; u < 4; ++u) {
        int idx = t * 4 + u;
        if (idx < NCH) cnthist[i * NCH1 + idx] = base;
        base += v[u];
    }
    if (t == 255) {                        // base here == bin total
        cnthist[i * NCH1 + NCH] = base;    // sentinel column
        colsum[i] = base;
    }
}

// Pass 3: scan of 391 bin totals -> binbase (single block)
__global__ __launch_bounds__(512) void k_scanbins(const int* __restrict__ colsum,
                                                  int* __restrict__ binbase) {
    __shared__ int wtot[8];
    int t = threadIdx.x;
    int v = (t < NB) ? colsum[t] : 0;
    int pre = blkexcl512(v, wtot);
    if (t < NB) binbase[t] = pre;
    if (t == 0) binbase[NB] = N_EDGES;   // sentinel
}

// Pass 4: scatter edges into bin buckets.  Per-chunk per-bin counts come from
// the scanned cnthist (pre[blk+1]-pre[blk]) -- no edge-decode pre-pass.
// Single edge pass sorts into LDS, then linear dump (clustered writes).
__global__ __launch_bounds__(512) void k_binscatter(const int* __restrict__ ei,
                                                    const int* __restrict__ binbase,
                                                    const int* __restrict__ cnthist,
                                                    unsigned* __restrict__ binbuf) {
    __shared__ unsigned       srecS[CHUNK];  // records at sorted position (24KB)
    __shared__ unsigned short sbinS[CHUNK];  // bin at sorted position     (12KB)
    __shared__ int h[NB], rl[NB], gb[NB];
    __shared__ int wtot[8];
    int t = threadIdx.x;
    int b0 = blockIdx.x * CHUNK;
    int n = N_EDGES - b0; if (n > CHUNK) n = CHUNK;
    int pre_b = 0, c = 0;
    if (t < NB) {
        pre_b = cnthist[t * NCH1 + blockIdx.x];
        c = cnthist[t * NCH1 + blockIdx.x + 1] - pre_b;
    }
    int rlv = blkexcl512(c, wtot);   // chunk-local sorted base per bin
    if (t < NB) {
        rl[t] = rlv;
        gb[t] = binbase[t] + pre_b;  // global dump base
        h[t] = 0;                    // cursor
    }
    __syncthreads();
    for (int e = t; e < n; e += 512) {
        int d = ei[N_EDGES + b0 + e];
        int s = ei[b0 + e];
        int b = d >> BINSHIFT;
        int p = rl[b] + atomicAdd(&h[b], 1);
        srecS[p] = (unsigned)s | ((unsigned)(d & (BINSZ - 1)) << 17);  // s < 2^17
        sbinS[p] = (unsigned short)b;
    }
    __syncthreads();
    for (int p = t; p < n; p += 512) {
        int b = sbinS[p];
        binbuf[gb[b] + (p - rl[b])] = srecS[p];
    }
}

// Pass 5: per-bin counting sort -> csr_src, rowstart, dinv; bin records staged
// in LDS on the count pass.  FUSED xw1 epilogue: this (bin,half) block owns
// 128 consecutive nodes -> after the scatter loop it emits
// XWH1[node][:] = fp16(dinv .* (x[node] @ W1)) for them (independent memory,
// no extra barrier; sdinv/sx/sW covered by the pre-scatter sync).
__global__ __launch_bounds__(512) void k_binfill(const unsigned* __restrict__ binbuf,
                                                 const int* __restrict__ binbase,
                                                 int* __restrict__ rowstart,
                                                 float* __restrict__ dinv,
                                                 int* __restrict__ csr_src,
                                                 const float* __restrict__ x,
                                                 const float* __restrict__ W1,
                                                 __half* __restrict__ xwh1) {
    int bb = blockIdx.x;
    int b = bb >> 1;        // bin
    int half = bb & 1;      // node range [half*128, half*128+128)
    int t = threadIdx.x;
    __shared__ unsigned srec[FCAP];   // 36KB staging
    __shared__ int cnt[BINSZ], rloc[BINSZ], cur[BINSZ], wtot[8];
    __shared__ float sW[IN_DIM * HID];      // 1408B
    __shared__ float sx[128 * IN_DIM];      // 5632B
    __shared__ float sdinv[128];
    int base_node = b * BINSZ + half * 128;
    // stage W1 + x slice for the fused xw1 (before first barrier)
    for (int i = t; i < IN_DIM * HID; i += 512) sW[i] = W1[i];
    for (int i = t; i < 128 * IN_DIM; i += 512) {
        int gi = base_node * IN_DIM + i;
        if (gi < N_NODES * IN_DIM) sx[i] = x[gi];
    }
    int ebeg = binbase[b], eend = binbase[b + 1];
    int m = eend - ebeg;
    if (t < BINSZ) cnt[t] = 0;
    __syncthreads();
    for (int e = t; e < m; e += 512) {
        unsigned v = binbuf[ebeg + e];
        if (e < FCAP) srec[e] = v;
        atomicAdd(&cnt[v >> 17], 1);
    }
    __syncthreads();
    int c = (t < BINSZ) ? cnt[t] : 0;
    int pre = blkexcl512(c, wtot);
    if (t < BINSZ) {
        rloc[t] = pre;
        cur[t] = 0;
        int node = b * BINSZ + t;
        if ((t >> 7) == half && node < N_NODES) {
            rowstart[node] = ebeg + pre;
            float dd = rsqrtf((float)c + 1.0f);  // +1 self-loop
            dinv[node] = dd;
            sdinv[t - half * 128] = dd;
        }
    }
    if (bb == 0 && t == 0) rowstart[N_NODES] = N_EDGES;  // sentinel
    __syncthreads();
    for (int e = t; e < m; e += 512) {
        unsigned vv = (e < FCAP) ? srec[e] : binbuf[ebeg + e];
        int dl = vv >> 17;
        if ((dl >> 7) == half) {
            int p = ebeg + rloc[dl] + atomicAdd(&cur[dl], 1);
            csr_src[p] = (int)(vv & 0x1FFFFu);
        }
    }
    // fused xw1 epilogue: 128 nodes x 32 feats = 4096 outputs, 8 per thread
#pragma unroll
    for (int r = 0; r < 8; ++r) {
        int o = t + r * 512;
        int mm = o >> 5, j = o & 31;
        int node = base_node + mm;
        if (node < N_NODES) {
            float a = 0.0f;
#pragma unroll
            for (int k = 0; k < IN_DIM; ++k)
                a += sx[mm * IN_DIM + k] * sW[k * HID + j];
            xwh1[node * HID + j] = __float2half(sdinv[mm] * a);
        }
    }
}

// ---------------- wide edge gather (octet decomposition, r8-proven) ----------------
__device__ __forceinline__ void accum8(float* __restrict__ acc, const uint4 v) {
    float2 f0 = __half22float2(*(const __half2*)&v.x);
    float2 f1 = __half22float2(*(const __half2*)&v.y);
    float2 f2 = __half22float2(*(const __half2*)&v.z);
    float2 f3 = __half22float2(*(const __half2*)&v.w);
    acc[0] += f0.x; acc[1] += f0.y;
    acc[2] += f1.x; acc[3] += f1.y;
    acc[4] += f2.x; acc[5] += f2.y;
    acc[6] += f3.x; acc[7] += f3.y;
}

__device__ __forceinline__ void edge_accum8(int beg, int end, int q, int oj,
                                            const int* __restrict__ csr_src,
                                            const __half* __restrict__ xwh,
                                            float* __restrict__ acc) {
#pragma unroll
    for (int k = 0; k < 8; ++k) acc[k] = 0.0f;
    int e = beg;
    for (; e + 32 <= end; e += 32) {
        int s0 = csr_src[e + q];
        int s1 = csr_src[e + 8 + q];
        int s2 = csr_src[e + 16 + q];
        int s3 = csr_src[e + 24 + q];
        uint4 v0 = *(const uint4*)(xwh + ((s0 << 5) | oj));
        uint4 v1 = *(const uint4*)(xwh + ((s1 << 5) | oj));
        uint4 v2 = *(const uint4*)(xwh + ((s2 << 5) | oj));
        uint4 v3 = *(const uint4*)(xwh + ((s3 << 5) | oj));
        accum8(acc, v0); accum8(acc, v1); accum8(acc, v2); accum8(acc, v3);
    }
    if (e + 16 <= end) {
        int s0 = csr_src[e + q];
        int s1 = csr_src[e + 8 + q];
        uint4 v0 = *(const uint4*)(xwh + ((s0 << 5) | oj));
        uint4 v1 = *(const uint4*)(xwh + ((s1 << 5) | oj));
        accum8(acc, v0); accum8(acc, v1);
        e += 16;
    }
    if (e + 8 <= end) {
        int s0 = csr_src[e + q];
        uint4 v0 = *(const uint4*)(xwh + ((s0 << 5) | oj));
        accum8(acc, v0);
        e += 8;
    }
    if (e + q < end) {  // masked tail
        int s0 = csr_src[e + q];
        uint4 v0 = *(const uint4*)(xwh + ((s0 << 5) | oj));
        accum8(acc, v0);
    }
#pragma unroll
    for (int m = 4; m <= 16; m <<= 1) {
#pragma unroll
        for (int k = 0; k < 8; ++k) acc[k] += __shfl_xor(acc[k], m);
    }
}

// ---------------- layer-1 gather fused with bias1+relu and the W2 transform ---------------
__global__ __launch_bounds__(256) void k_gather_xw2(const int* __restrict__ rowstart,
                                                    const float* __restrict__ dinv,
                                                    const int* __restrict__ csr_src,
                                                    const __half* __restrict__ xwh1,
                                                    const float* __restrict__ b1,
                                                    const float* __restrict__ W2,
                                                    __half* __restrict__ xwh2) {
    __shared__ float sW2[HID * HID];
    __shared__ float sA[8][33];
    __shared__ float sH[8][33];
    for (int i = threadIdx.x; i < HID * HID; i += 256) sW2[i] = W2[i];

    int ln = threadIdx.x >> 5;
    int node = blockIdx.x * 8 + ln;
    int l = threadIdx.x & 31;
    int q = l >> 2;
    int oj = (l & 3) << 3;

    float acc[8];
    edge_accum8(rowstart[node], rowstart[node + 1], q, oj, csr_src, xwh1, acc);
    if (q == 0) {
#pragma unroll
        for (int k = 0; k < 8; ++k) sA[ln][oj + k] = acc[k];
    }
    __syncthreads();

    int j = l;
    float dd = dinv[node];
    float hv = dd * (sA[ln][j] + __half2float(xwh1[node * HID + j])) + b1[j];
    sH[ln][j] = hv > 0.0f ? hv : 0.0f;
    __syncthreads();

    float a2 = 0.0f;
#pragma unroll
    for (int k = 0; k < HID; ++k) a2 += sH[ln][k] * sW2[k * HID + j];
    xwh2[node * HID + j] = __float2half(dd * a2);
}

// ---------------- layer-2 gather fused with bias2+relu and the output MLP ----------------
__global__ __launch_bounds__(256) void k_gather_mlp(const int* __restrict__ rowstart,
                                                    const float* __restrict__ dinv,
                                                    const int* __restrict__ csr_src,
                                                    const __half* __restrict__ xwh,
                                                    const float* __restrict__ b2,
                                                    const float* __restrict__ Wo1,
                                                    const float* __restrict__ bo1,
                                                    const float* __restrict__ Wo2,
                                                    const float* __restrict__ bo2,
                                                    float* __restrict__ out) {
    __shared__ float sW1[HID * HID2];
    __shared__ float sb1[HID2];
    __shared__ float sW2v[HID2];
    __shared__ float sb2[HID];
    __shared__ float sA[8][33];
    __shared__ float sH[8][33];
    for (int i = threadIdx.x; i < HID * HID2; i += 256) sW1[i] = Wo1[i];
    if (threadIdx.x < HID2) {
        sb1[threadIdx.x] = bo1[threadIdx.x];
        sW2v[threadIdx.x] = Wo2[threadIdx.x];
    }
    if (threadIdx.x < HID) sb2[threadIdx.x] = b2[threadIdx.x];

    int ln = threadIdx.x >> 5;
    int node = blockIdx.x * 8 + ln;
    int l = threadIdx.x & 31;
    int q = l >> 2;
    int oj = (l & 3) << 3;

    float acc[8];
    edge_accum8(rowstart[node], rowstart[node + 1], q, oj, csr_src, xwh, acc);
    if (q == 0) {
#pragma unroll
        for (int k = 0; k < 8; ++k) sA[ln][oj + k] = acc[k];
    }
    __syncthreads();

    int j = l;
    float dd = dinv[node];
    float hv = dd * (sA[ln][j] + __half2float(xwh[node * HID + j])) + sb2[j];
    sH[ln][j] = hv > 0.0f ? hv : 0.0f;
    __syncthreads();

    float val = 0.0f;
    if (j < HID2) {
        float a = sb1[j];
#pragma unroll
        for (int k = 0; k < HID; ++k) a += sH[ln][k] * sW1[k * HID2 + j];
        a = a > 0.0f ? a : (expf(a) - 1.0f);  // elu alpha=1
        val = a * sW2v[j];
    }
#pragma unroll
    for (int d = 16; d >= 1; d >>= 1) val += __shfl_down(val, d, 32);
    if (j == 0) out[node] = val + bo2[0];
}

extern "C" void kernel_launch(void* const* d_in, const int* in_sizes, int n_in,
                              void* d_out, int out_size, void* d_ws, size_t ws_size,
                              hipStream_t stream) {
    const float* x   = (const float*)d_in[0];
    const int*   ei  = (const int*)d_in[1];
    const float* W1  = (const float*)d_in[3];
    const float* b1  = (const float*)d_in[4];
    const float* W2  = (const float*)d_in[5];
    const float* b2  = (const float*)d_in[6];
    const float* Wo1 = (const float*)d_in[7];
    const float* bo1 = (const float*)d_in[8];
    const float* Wo2 = (const float*)d_in[9];
    const float* bo2 = (const float*)d_in[10];
    float* out = (float*)d_out;

    // ws layout (4B units):
    // colsum[512] | binbase[512] | rowstart[SCHUNK] | dinv[SCHUNK]
    // | csr_src[E] (cnthist[NB*NCH1]=204102 ints aliases here; dead before binfill writes)
    // | binbuf[E] | XWH1[N*HID fp16] | XWH2[N*HID fp16]
    int*      colsum   = (int*)d_ws;
    int*      binbase  = colsum + 512;
    int*      rowstart = binbase + 512;
    float*    dinv     = (float*)(rowstart + SCHUNK);
    int*      csr_src  = (int*)(dinv + SCHUNK);
    unsigned* binbuf   = (unsigned*)(csr_src + N_EDGES);
    __half*   XWH1     = (__half*)(binbuf + N_EDGES);
    __half*   XWH2     = XWH1 + (size_t)N_NODES * HID;
    int*      cnthist  = csr_src;   // alias: NB*NCH1 = 204102 ints << N_EDGES

    const int BT = 256;
    int gG = N_NODES / 8;   // 12500 (exact)

    // binned CSR build: hist -> colscan(+sentinel) -> binscan -> scatter
    // -> fill (+fused xw1)
    k_hist      <<<NCH, BT, 0, stream>>>(ei, cnthist);
    k_colscan   <<<NB, BT, 0, stream>>>(cnthist, colsum);
    k_scanbins  <<<1, 512, 0, stream>>>(colsum, binbase);
    k_binscatter<<<NCH, 512, 0, stream>>>(ei, binbase, cnthist, binbuf);
    k_binfill   <<<2 * NB, 512, 0, stream>>>(binbuf, binbase, rowstart, dinv,
                                             csr_src, x, W1, XWH1);

    // layer 1 (+ fused W2): XWH2 = fp16(dinv.*(relu(gather+b1)@W2))
    k_gather_xw2<<<gG, BT, 0, stream>>>(rowstart, dinv, csr_src, XWH1, b1, W2, XWH2);

    // layer 2 + head: out = MLP(relu(dinv.*gather(XWH2) + b2))
    k_gather_mlp<<<gG, BT, 0, stream>>>(rowstart, dinv, csr_src, XWH2,
                                        b2, Wo1, bo1, Wo2, bo2, out);
}